// Round 1
// baseline (1117.376 us; speedup 1.0000x reference)
//
#include <hip/hip_runtime.h>
#include <hip/hip_bf16.h>

// Problem constants (fixed by the reference).
constexpr int NN   = 10000;   // nodes
constexpr int NE   = 160000;  // edges
constexpr int INC  = 256;     // in channels
constexpr int HIDC = 128;     // hidden per head
constexpr int H    = 8;       // heads (layer 1)
constexpr int D1   = H * HIDC; // 1024
constexpr int OUTC = 32;      // layer-2 out channels
constexpr float NEG_SLOPE = 0.2f;

// ---- float <-> monotonic uint for atomicMax on floats ----
__device__ __forceinline__ unsigned f2u_mono(float f) {
  unsigned u = __float_as_uint(f);
  return (u & 0x80000000u) ? ~u : (u | 0x80000000u);
}
__device__ __forceinline__ float u2f_mono(unsigned u) {
  return (u & 0x80000000u) ? __uint_as_float(u & 0x7FFFFFFFu) : __uint_as_float(~u);
}
// encode(-inf) = ~0xFF800000 = 0x007FFFFF
#define NEG_INF_KEY 0x007FFFFFu

// ---------------- init workspace ----------------
__global__ void init_ws(float* __restrict__ h1, float* __restrict__ den1,
                        unsigned* __restrict__ nmax1, float* __restrict__ den2,
                        unsigned* __restrict__ nmax2, float* __restrict__ out) {
  int i = blockIdx.x * 256 + threadIdx.x;
  if (i < NN * D1) h1[i] = 0.f;
  if (i < NN * H) { den1[i] = 0.f; nmax1[i] = NEG_INF_KEY; }
  if (i < NN)     { den2[i] = 0.f; nmax2[i] = NEG_INF_KEY; }
  if (i < NN * OUTC) out[i] = 0.f;
}

// ---------------- tiled fp32 GEMM: C[M,N] = A[M,K] @ B[K,N] ----------------
// Requires N%64==0, K%16==0. M guarded.
__global__ __launch_bounds__(256) void gemm_f32(const float* __restrict__ A,
                                                const float* __restrict__ B,
                                                float* __restrict__ C,
                                                int M, int N, int K) {
  __shared__ float As[16][65];
  __shared__ float Bs[16][65];
  const int t = threadIdx.x;
  const int tx = t & 15, ty = t >> 4;
  const int row0 = blockIdx.y * 64, col0 = blockIdx.x * 64;
  float acc[4][4] = {};
  for (int k0 = 0; k0 < K; k0 += 16) {
    { // A tile: 64 rows x 16 k; each thread loads float4 of k
      int m = t >> 2;
      int kk = (t & 3) * 4;
      int gr = row0 + m;
      float4 v = make_float4(0.f, 0.f, 0.f, 0.f);
      if (gr < M) v = *(const float4*)(A + (long long)gr * K + k0 + kk);
      As[kk + 0][m] = v.x; As[kk + 1][m] = v.y; As[kk + 2][m] = v.z; As[kk + 3][m] = v.w;
    }
    { // B tile: 16 k x 64 cols; each thread loads float4 of cols
      int kk = t >> 4;
      int c = (t & 15) * 4;
      float4 v = *(const float4*)(B + (long long)(k0 + kk) * N + col0 + c);
      Bs[kk][c] = v.x; Bs[kk][c + 1] = v.y; Bs[kk][c + 2] = v.z; Bs[kk][c + 3] = v.w;
    }
    __syncthreads();
#pragma unroll
    for (int kk = 0; kk < 16; kk++) {
      float a[4], b[4];
#pragma unroll
      for (int i = 0; i < 4; i++) a[i] = As[kk][ty + 16 * i];
#pragma unroll
      for (int j = 0; j < 4; j++) b[j] = Bs[kk][tx + 16 * j];
#pragma unroll
      for (int i = 0; i < 4; i++)
#pragma unroll
        for (int j = 0; j < 4; j++) acc[i][j] += a[i] * b[j];
    }
    __syncthreads();
  }
#pragma unroll
  for (int i = 0; i < 4; i++) {
    int r = row0 + ty + 16 * i;
    if (r < M) {
#pragma unroll
      for (int j = 0; j < 4; j++) C[(long long)r * N + col0 + tx + 16 * j] = acc[i][j];
    }
  }
}

// ---------------- layer-1 edge pass 1: e scores + segment max ----------------
// one wave (64 lanes) per edge
__global__ __launch_bounds__(256) void edge1_e(const int* __restrict__ src, const int* __restrict__ dst,
                                               const float* __restrict__ xl, const float* __restrict__ xr,
                                               const float* __restrict__ att, float* __restrict__ e1,
                                               unsigned* __restrict__ nmax) {
  int lane = threadIdx.x & 63;
  int e = blockIdx.x * 4 + (threadIdx.x >> 6);
  if (e >= NE) return;
  int s = src[e], d = dst[e];
  const float* xls = xl + (long long)s * D1;
  const float* xrd = xr + (long long)d * D1;
  float acc[8];
#pragma unroll
  for (int h = 0; h < 8; h++) {
    int b = h * 128 + lane;
    float a0 = xls[b] + xrd[b];
    float a1 = xls[b + 64] + xrd[b + 64];
    a0 = a0 > 0.f ? a0 : NEG_SLOPE * a0;
    a1 = a1 > 0.f ? a1 : NEG_SLOPE * a1;
    acc[h] = a0 * att[b] + a1 * att[b + 64];
  }
#pragma unroll
  for (int h = 0; h < 8; h++) {
    float v = acc[h];
#pragma unroll
    for (int off = 32; off > 0; off >>= 1) v += __shfl_xor(v, off);
    acc[h] = v;
  }
  if (lane == 0) {
#pragma unroll
    for (int h = 0; h < 8; h++) {
      e1[e * 8 + h] = acc[h];
      atomicMax(&nmax[d * 8 + h], f2u_mono(acc[h]));
    }
  }
}

// ---------------- layer-1 edge pass 2: exp + denom ----------------
__global__ void edge1_norm(const int* __restrict__ dst, const unsigned* __restrict__ nmax,
                           float* __restrict__ e1, float* __restrict__ den) {
  int i = blockIdx.x * 256 + threadIdx.x;
  if (i >= NE * H) return;
  int e = i >> 3, h = i & 7;
  int d = dst[e];
  float m = u2f_mono(nmax[d * 8 + h]);
  float ex = expf(e1[i] - m);
  e1[i] = ex;
  atomicAdd(&den[d * 8 + h], ex);
}

// ---------------- layer-1 edge pass 3: weighted scatter-add ----------------
__global__ __launch_bounds__(256) void edge1_agg(const int* __restrict__ src, const int* __restrict__ dst,
                                                 const float* __restrict__ xl, const float* __restrict__ e1,
                                                 const float* __restrict__ den, float* __restrict__ out1) {
  int lane = threadIdx.x & 63;
  int e = blockIdx.x * 4 + (threadIdx.x >> 6);
  if (e >= NE) return;
  int s = src[e], d = dst[e];
  const float* xls = xl + (long long)s * D1;
  float* od = out1 + (long long)d * D1;
#pragma unroll
  for (int h = 0; h < 8; h++) {
    float alpha = e1[e * 8 + h] / (den[d * 8 + h] + 1e-16f);
    int b = h * 128 + lane;
    atomicAdd(&od[b], xls[b] * alpha);
    atomicAdd(&od[b + 64], xls[b + 64] * alpha);
  }
}

// ---------------- ELU(+bias) in place ----------------
__global__ void elu_bias(float* __restrict__ h1, const float* __restrict__ b1) {
  int i = blockIdx.x * 256 + threadIdx.x;
  if (i >= NN * D1) return;
  float v = h1[i] + b1[i & (D1 - 1)];
  h1[i] = v > 0.f ? v : expm1f(v);
}

// ---------------- layer-2 GEMMs (row per block) ----------------
__global__ __launch_bounds__(64) void gemm2_rows(const float* __restrict__ h1,
                                                 const float* __restrict__ W2l,
                                                 const float* __restrict__ W2r,
                                                 float* __restrict__ xl2, float* __restrict__ xr2) {
  __shared__ float row[D1];
  int m = blockIdx.x, t = threadIdx.x;
  const float4* hr = (const float4*)(h1 + (long long)m * D1);
  float4* r4 = (float4*)row;
  for (int i = t; i < D1 / 4; i += 64) r4[i] = hr[i];
  __syncthreads();
  const float* W = (t < 32) ? W2l : W2r;
  int col = t & 31;
  float acc = 0.f;
#pragma unroll 8
  for (int k = 0; k < D1; k++) acc += row[k] * W[k * 32 + col];
  if (t < 32) xl2[m * 32 + col] = acc;
  else        xr2[m * 32 + col] = acc;
}

// ---------------- layer-2 edge pass 1 (half-wave per edge) ----------------
__global__ __launch_bounds__(256) void edge2_e(const int* __restrict__ src, const int* __restrict__ dst,
                                               const float* __restrict__ xl2, const float* __restrict__ xr2,
                                               const float* __restrict__ att2, float* __restrict__ e2,
                                               unsigned* __restrict__ nmax2) {
  int t = threadIdx.x;
  int e = blockIdx.x * 8 + (t >> 5);
  int c = t & 31;
  if (e >= NE) return;
  int s = src[e], d = dst[e];
  float a = xl2[s * 32 + c] + xr2[d * 32 + c];
  a = a > 0.f ? a : NEG_SLOPE * a;
  float v = a * att2[c];
#pragma unroll
  for (int off = 16; off > 0; off >>= 1) v += __shfl_xor(v, off);
  if (c == 0) {
    e2[e] = v;
    atomicMax(&nmax2[d], f2u_mono(v));
  }
}

__global__ void edge2_norm(const int* __restrict__ dst, const unsigned* __restrict__ nmax2,
                           float* __restrict__ e2, float* __restrict__ den2) {
  int e = blockIdx.x * 256 + threadIdx.x;
  if (e >= NE) return;
  int d = dst[e];
  float m = u2f_mono(nmax2[d]);
  float ex = expf(e2[e] - m);
  e2[e] = ex;
  atomicAdd(&den2[d], ex);
}

__global__ __launch_bounds__(256) void edge2_agg(const int* __restrict__ src, const int* __restrict__ dst,
                                                 const float* __restrict__ xl2, const float* __restrict__ e2,
                                                 const float* __restrict__ den2, float* __restrict__ out) {
  int t = threadIdx.x;
  int e = blockIdx.x * 8 + (t >> 5);
  int c = t & 31;
  if (e >= NE) return;
  int s = src[e], d = dst[e];
  float alpha = e2[e] / (den2[d] + 1e-16f);
  atomicAdd(&out[d * 32 + c], xl2[s * 32 + c] * alpha);
}

// ---------------- log_softmax (+bias), half-wave per row, in place ----------------
__global__ __launch_bounds__(256) void logsm(float* __restrict__ out, const float* __restrict__ b2) {
  int t = threadIdx.x;
  int n = blockIdx.x * 8 + (t >> 5);
  int c = t & 31;
  if (n >= NN) return;
  float v = out[n * 32 + c] + b2[c];
  float m = v;
#pragma unroll
  for (int off = 16; off > 0; off >>= 1) m = fmaxf(m, __shfl_xor(m, off));
  float ex = expf(v - m);
  float s = ex;
#pragma unroll
  for (int off = 16; off > 0; off >>= 1) s += __shfl_xor(s, off);
  out[n * 32 + c] = v - m - logf(s);
}

extern "C" void kernel_launch(void* const* d_in, const int* in_sizes, int n_in,
                              void* d_out, int out_size, void* d_ws, size_t ws_size,
                              hipStream_t stream) {
  const float* x    = (const float*)d_in[0];
  const int*   ei   = (const int*)d_in[1];
  const float* W1l  = (const float*)d_in[2];
  const float* W1r  = (const float*)d_in[3];
  const float* att1 = (const float*)d_in[4];
  const float* b1   = (const float*)d_in[5];
  const float* W2l  = (const float*)d_in[6];
  const float* W2r  = (const float*)d_in[7];
  const float* att2 = (const float*)d_in[8];
  const float* b2   = (const float*)d_in[9];
  float* out = (float*)d_out;

  // workspace layout (floats)
  float* xl1 = (float*)d_ws;            // NN*D1
  float* xr1 = xl1 + (size_t)NN * D1;   // NN*D1
  float* h1  = xr1 + (size_t)NN * D1;   // NN*D1 (accumulator, then h after ELU)
  float* e1  = h1 + (size_t)NN * D1;    // NE*H
  float* den1 = e1 + (size_t)NE * H;    // NN*H
  unsigned* nmax1 = (unsigned*)(den1 + (size_t)NN * H); // NN*H
  float* e2  = (float*)(nmax1 + (size_t)NN * H);        // NE
  float* den2 = e2 + NE;                // NN
  unsigned* nmax2 = (unsigned*)(den2 + NN);             // NN
  float* xl2 = (float*)(nmax2 + NN);    // NN*OUTC
  float* xr2 = xl2 + (size_t)NN * OUTC; // NN*OUTC

  const int* src = ei;
  const int* dst = ei + NE;

  // 1. init accumulators
  init_ws<<<(NN * D1 + 255) / 256, 256, 0, stream>>>(h1, den1, nmax1, den2, nmax2, out);

  // 2. layer-1 GEMMs
  dim3 g1(D1 / 64, (NN + 63) / 64);
  gemm_f32<<<g1, 256, 0, stream>>>(x, W1l, xl1, NN, D1, INC);
  gemm_f32<<<g1, 256, 0, stream>>>(x, W1r, xr1, NN, D1, INC);

  // 3-5. layer-1 edge passes
  edge1_e<<<NE / 4, 256, 0, stream>>>(src, dst, xl1, xr1, att1, e1, nmax1);
  edge1_norm<<<(NE * H + 255) / 256, 256, 0, stream>>>(dst, nmax1, e1, den1);
  edge1_agg<<<NE / 4, 256, 0, stream>>>(src, dst, xl1, e1, den1, h1);

  // 6. ELU + bias
  elu_bias<<<(NN * D1 + 255) / 256, 256, 0, stream>>>(h1, b1);

  // 7. layer-2 GEMMs
  gemm2_rows<<<NN, 64, 0, stream>>>(h1, W2l, W2r, xl2, xr2);

  // 8. layer-2 edge passes
  edge2_e<<<NE / 8, 256, 0, stream>>>(src, dst, xl2, xr2, att2, e2, nmax2);
  edge2_norm<<<(NE + 255) / 256, 256, 0, stream>>>(dst, nmax2, e2, den2);
  edge2_agg<<<NE / 8, 256, 0, stream>>>(src, dst, xl2, e2, den2, out);

  // 9. log_softmax
  logsm<<<(NN + 7) / 8, 256, 0, stream>>>(out, b2);
}

// Round 2
// 811.069 us; speedup vs baseline: 1.3777x; 1.3777x over previous
//
#include <hip/hip_runtime.h>
#include <hip/hip_bf16.h>

constexpr int NN   = 10000;
constexpr int NE   = 160000;
constexpr int INC  = 256;
constexpr int HIDC = 128;
constexpr int H    = 8;
constexpr int D1   = H * HIDC; // 1024
constexpr int OUTC = 32;
constexpr float NEG_SLOPE = 0.2f;

// ---------------- CSR build ----------------
__global__ void zero_deg(int* __restrict__ deg) {
  int i = blockIdx.x * 256 + threadIdx.x;
  if (i < NN) deg[i] = 0;
}

__global__ void deg_hist(const int* __restrict__ dst, int* __restrict__ deg) {
  int e = blockIdx.x * 256 + threadIdx.x;
  if (e < NE) atomicAdd(&deg[dst[e]], 1);
}

// single wave exclusive scan -> rowptr[NN+1]
__global__ __launch_bounds__(64) void scan_rowptr(const int* __restrict__ deg,
                                                  int* __restrict__ rowptr) {
  int lane = threadIdx.x;
  int carry = 0;
  for (int base = 0; base < NN; base += 64) {
    int i = base + lane;
    int v = (i < NN) ? deg[i] : 0;
    int s = v;
#pragma unroll
    for (int off = 1; off < 64; off <<= 1) {
      int t = __shfl_up(s, off);
      if (lane >= off) s += t;
    }
    if (i < NN) rowptr[i] = carry + s - v;
    carry += __shfl(s, 63);
  }
  if (lane == 0) rowptr[NN] = carry;
}

__global__ void copy_cursor(const int* __restrict__ rowptr, int* __restrict__ cursor) {
  int i = blockIdx.x * 256 + threadIdx.x;
  if (i < NN) cursor[i] = rowptr[i];
}

__global__ void csr_fill(const int* __restrict__ dst, int* __restrict__ cursor,
                         int* __restrict__ csr_e) {
  int e = blockIdx.x * 256 + threadIdx.x;
  if (e >= NE) return;
  int pos = atomicAdd(&cursor[dst[e]], 1);
  csr_e[pos] = e;
}

// ---------------- tiled fp32 GEMM: C[M,N] = A[M,K] @ B[K,N] ----------------
// Requires N%64==0, K%16==0. M guarded.
__global__ __launch_bounds__(256) void gemm_f32(const float* __restrict__ A,
                                                const float* __restrict__ B,
                                                float* __restrict__ C,
                                                int M, int N, int K) {
  __shared__ float As[16][65];
  __shared__ float Bs[16][65];
  const int t = threadIdx.x;
  const int tx = t & 15, ty = t >> 4;
  const int row0 = blockIdx.y * 64, col0 = blockIdx.x * 64;
  float acc[4][4] = {};
  for (int k0 = 0; k0 < K; k0 += 16) {
    {
      int m = t >> 2;
      int kk = (t & 3) * 4;
      int gr = row0 + m;
      float4 v = make_float4(0.f, 0.f, 0.f, 0.f);
      if (gr < M) v = *(const float4*)(A + (long long)gr * K + k0 + kk);
      As[kk + 0][m] = v.x; As[kk + 1][m] = v.y; As[kk + 2][m] = v.z; As[kk + 3][m] = v.w;
    }
    {
      int kk = t >> 4;
      int c = (t & 15) * 4;
      float4 v = *(const float4*)(B + (long long)(k0 + kk) * N + col0 + c);
      Bs[kk][c] = v.x; Bs[kk][c + 1] = v.y; Bs[kk][c + 2] = v.z; Bs[kk][c + 3] = v.w;
    }
    __syncthreads();
#pragma unroll
    for (int kk = 0; kk < 16; kk++) {
      float a[4], b[4];
#pragma unroll
      for (int i = 0; i < 4; i++) a[i] = As[kk][ty + 16 * i];
#pragma unroll
      for (int j = 0; j < 4; j++) b[j] = Bs[kk][tx + 16 * j];
#pragma unroll
      for (int i = 0; i < 4; i++)
#pragma unroll
        for (int j = 0; j < 4; j++) acc[i][j] += a[i] * b[j];
    }
    __syncthreads();
  }
#pragma unroll
  for (int i = 0; i < 4; i++) {
    int r = row0 + ty + 16 * i;
    if (r < M) {
#pragma unroll
      for (int j = 0; j < 4; j++) C[(long long)r * N + col0 + tx + 16 * j] = acc[i][j];
    }
  }
}

// ---------------- layer-1 edge scores (wave per edge) ----------------
__global__ __launch_bounds__(256) void edge1_e(const int* __restrict__ src, const int* __restrict__ dst,
                                               const float* __restrict__ xl, const float* __restrict__ xr,
                                               const float* __restrict__ att, float* __restrict__ e1) {
  int lane = threadIdx.x & 63;
  int e = blockIdx.x * 4 + (threadIdx.x >> 6);
  if (e >= NE) return;
  int s = src[e], d = dst[e];
  const float* xls = xl + (long long)s * D1;
  const float* xrd = xr + (long long)d * D1;
  float acc[8];
#pragma unroll
  for (int h = 0; h < 8; h++) {
    int b = h * 128 + lane;
    float a0 = xls[b] + xrd[b];
    float a1 = xls[b + 64] + xrd[b + 64];
    a0 = a0 > 0.f ? a0 : NEG_SLOPE * a0;
    a1 = a1 > 0.f ? a1 : NEG_SLOPE * a1;
    acc[h] = a0 * att[b] + a1 * att[b + 64];
  }
#pragma unroll
  for (int h = 0; h < 8; h++) {
    float v = acc[h];
#pragma unroll
    for (int off = 32; off > 0; off >>= 1) v += __shfl_xor(v, off);
    acc[h] = v;
  }
  if (lane == 0) {
#pragma unroll
    for (int h = 0; h < 8; h++) e1[e * 8 + h] = acc[h];
  }
}

// ---------------- layer-1 segment softmax via CSR: e1 -> alpha in place ----------------
__global__ void node1_softmax(const int* __restrict__ rowptr, const int* __restrict__ csr_e,
                              float* __restrict__ e1) {
  int i = blockIdx.x * 256 + threadIdx.x;
  if (i >= NN * H) return;
  int d = i >> 3, h = i & 7;
  int jb = rowptr[d], je = rowptr[d + 1];
  if (jb == je) return;
  float m = -3.4e38f;
  for (int j = jb; j < je; j++) m = fmaxf(m, e1[csr_e[j] * 8 + h]);
  float s = 0.f;
  for (int j = jb; j < je; j++) s += expf(e1[csr_e[j] * 8 + h] - m);
  float inv = 1.f / (s + 1e-16f);
  for (int j = jb; j < je; j++) {
    int e = csr_e[j];
    e1[e * 8 + h] = expf(e1[e * 8 + h] - m) * inv;
  }
}

// ---------------- layer-1 gather aggregation + bias + ELU (block per dst node) ----------------
__global__ __launch_bounds__(256) void agg1(const int* __restrict__ rowptr, const int* __restrict__ csr_e,
                                            const int* __restrict__ src, const float* __restrict__ xl,
                                            const float* __restrict__ e1, const float* __restrict__ b1,
                                            float* __restrict__ h1) {
  int d = blockIdx.x;
  int t = threadIdx.x;
  int ch = t * 4;
  int head = t >> 5;
  float4 acc = make_float4(0.f, 0.f, 0.f, 0.f);
  int jb = rowptr[d], je = rowptr[d + 1];
  for (int j = jb; j < je; j++) {
    int e = csr_e[j];
    int s = src[e];
    float alpha = e1[e * 8 + head];
    float4 v = *(const float4*)(xl + (long long)s * D1 + ch);
    acc.x += alpha * v.x; acc.y += alpha * v.y;
    acc.z += alpha * v.z; acc.w += alpha * v.w;
  }
  float4 b = *(const float4*)(b1 + ch);
  acc.x += b.x; acc.y += b.y; acc.z += b.z; acc.w += b.w;
  acc.x = acc.x > 0.f ? acc.x : expm1f(acc.x);
  acc.y = acc.y > 0.f ? acc.y : expm1f(acc.y);
  acc.z = acc.z > 0.f ? acc.z : expm1f(acc.z);
  acc.w = acc.w > 0.f ? acc.w : expm1f(acc.w);
  *(float4*)(h1 + (long long)d * D1 + ch) = acc;
}

// ---------------- concat W2l|W2r -> [1024][64] ----------------
__global__ void w2cat(const float* __restrict__ W2l, const float* __restrict__ W2r,
                      float* __restrict__ W2c) {
  int i = blockIdx.x * 256 + threadIdx.x;
  if (i >= D1 * 64) return;
  int k = i >> 6, c = i & 63;
  W2c[i] = (c < 32) ? W2l[k * 32 + c] : W2r[k * 32 + (c - 32)];
}

// ---------------- layer-2 edge scores (32 lanes per edge) ----------------
__global__ __launch_bounds__(256) void edge2_e(const int* __restrict__ src, const int* __restrict__ dst,
                                               const float* __restrict__ xlr2,
                                               const float* __restrict__ att2, float* __restrict__ e2) {
  int t = threadIdx.x;
  int e = blockIdx.x * 8 + (t >> 5);
  int c = t & 31;
  if (e >= NE) return;
  int s = src[e], d = dst[e];
  float a = xlr2[s * 64 + c] + xlr2[d * 64 + 32 + c];
  a = a > 0.f ? a : NEG_SLOPE * a;
  float v = a * att2[c];
#pragma unroll
  for (int off = 16; off > 0; off >>= 1) v += __shfl_xor(v, off);
  if (c == 0) e2[e] = v;
}

// ---------------- layer-2 segment softmax via CSR: e2 -> alpha in place ----------------
__global__ void node2_softmax(const int* __restrict__ rowptr, const int* __restrict__ csr_e,
                              float* __restrict__ e2) {
  int d = blockIdx.x * 256 + threadIdx.x;
  if (d >= NN) return;
  int jb = rowptr[d], je = rowptr[d + 1];
  if (jb == je) return;
  float m = -3.4e38f;
  for (int j = jb; j < je; j++) m = fmaxf(m, e2[csr_e[j]]);
  float s = 0.f;
  for (int j = jb; j < je; j++) s += expf(e2[csr_e[j]] - m);
  float inv = 1.f / (s + 1e-16f);
  for (int j = jb; j < je; j++) {
    int e = csr_e[j];
    e2[e] = expf(e2[e] - m) * inv;
  }
}

// ---------------- layer-2 gather agg + bias + log_softmax (32 lanes per dst) ----------------
__global__ __launch_bounds__(256) void agg2(const int* __restrict__ rowptr, const int* __restrict__ csr_e,
                                            const int* __restrict__ src, const float* __restrict__ xlr2,
                                            const float* __restrict__ e2, const float* __restrict__ b2,
                                            float* __restrict__ out) {
  int t = threadIdx.x;
  int d = blockIdx.x * 8 + (t >> 5);
  int c = t & 31;
  if (d >= NN) return;
  float acc = 0.f;
  int jb = rowptr[d], je = rowptr[d + 1];
  for (int j = jb; j < je; j++) {
    int e = csr_e[j];
    int s = src[e];
    acc += e2[e] * xlr2[s * 64 + c];
  }
  float v = acc + b2[c];
  float m = v;
#pragma unroll
  for (int off = 16; off > 0; off >>= 1) m = fmaxf(m, __shfl_xor(m, off));
  float ex = expf(v - m);
  float sum = ex;
#pragma unroll
  for (int off = 16; off > 0; off >>= 1) sum += __shfl_xor(sum, off);
  out[d * 32 + c] = v - m - logf(sum);
}

extern "C" void kernel_launch(void* const* d_in, const int* in_sizes, int n_in,
                              void* d_out, int out_size, void* d_ws, size_t ws_size,
                              hipStream_t stream) {
  const float* x    = (const float*)d_in[0];
  const int*   ei   = (const int*)d_in[1];
  const float* W1l  = (const float*)d_in[2];
  const float* W1r  = (const float*)d_in[3];
  const float* att1 = (const float*)d_in[4];
  const float* b1   = (const float*)d_in[5];
  const float* W2l  = (const float*)d_in[6];
  const float* W2r  = (const float*)d_in[7];
  const float* att2 = (const float*)d_in[8];
  const float* b2   = (const float*)d_in[9];
  float* out = (float*)d_out;

  // workspace layout
  float* xl1  = (float*)d_ws;                 // NN*D1
  float* xr1  = xl1 + (size_t)NN * D1;        // NN*D1 (reused as h1 after edge1_e)
  float* h1   = xr1;                          // alias: xr1 dead after edge1_e
  float* e1   = xr1 + (size_t)NN * D1;        // NE*H (scores -> alphas)
  float* e2   = e1 + (size_t)NE * H;          // NE
  float* xlr2 = e2 + NE;                      // NN*64 (cols 0-31 = xl2, 32-63 = xr2)
  float* W2c  = xlr2 + (size_t)NN * 64;       // D1*64
  int* deg    = (int*)(W2c + (size_t)D1 * 64);// NN
  int* rowptr = deg + NN;                     // NN+1
  int* cursor = rowptr + NN + 1;              // NN
  int* csr_e  = cursor + NN;                  // NE

  const int* src = ei;
  const int* dst = ei + NE;

  // CSR build
  zero_deg<<<(NN + 255) / 256, 256, 0, stream>>>(deg);
  deg_hist<<<(NE + 255) / 256, 256, 0, stream>>>(dst, deg);
  scan_rowptr<<<1, 64, 0, stream>>>(deg, rowptr);
  copy_cursor<<<(NN + 255) / 256, 256, 0, stream>>>(rowptr, cursor);
  csr_fill<<<(NE + 255) / 256, 256, 0, stream>>>(dst, cursor, csr_e);

  // layer-1 GEMMs
  dim3 g1(D1 / 64, (NN + 63) / 64);
  gemm_f32<<<g1, 256, 0, stream>>>(x, W1l, xl1, NN, D1, INC);
  gemm_f32<<<g1, 256, 0, stream>>>(x, W1r, xr1, NN, D1, INC);

  // layer-1 attention
  edge1_e<<<NE / 4, 256, 0, stream>>>(src, dst, xl1, xr1, att1, e1);
  node1_softmax<<<(NN * H + 255) / 256, 256, 0, stream>>>(rowptr, csr_e, e1);
  agg1<<<NN, 256, 0, stream>>>(rowptr, csr_e, src, xl1, e1, b1, h1);

  // layer-2 GEMM (combined l|r)
  w2cat<<<(D1 * 64 + 255) / 256, 256, 0, stream>>>(W2l, W2r, W2c);
  dim3 g2(1, (NN + 63) / 64);
  gemm_f32<<<g2, 256, 0, stream>>>(h1, W2c, xlr2, NN, 64, D1);

  // layer-2 attention
  edge2_e<<<NE / 8, 256, 0, stream>>>(src, dst, xlr2, att2, e2);
  node2_softmax<<<(NN + 255) / 256, 256, 0, stream>>>(rowptr, csr_e, e2);
  agg2<<<(NN + 7) / 8, 256, 0, stream>>>(rowptr, csr_e, src, xlr2, e2, b2, out);
}

// Round 3
// 510.171 us; speedup vs baseline: 2.1902x; 1.5898x over previous
//
#include <hip/hip_runtime.h>
#include <hip/hip_bf16.h>

constexpr int NN   = 10000;
constexpr int NE   = 160000;
constexpr int INC  = 256;
constexpr int H    = 8;
constexpr int D1   = 1024;     // 8 heads x 128
constexpr int OUTC = 32;
constexpr int MPAD = 10112;    // 79 * 128
constexpr float NEG_SLOPE = 0.2f;

typedef __attribute__((ext_vector_type(8))) short bf16x8;
typedef __attribute__((ext_vector_type(4))) float f32x4;

__device__ __forceinline__ unsigned short f2b(float f) {
  unsigned u = __float_as_uint(f);
  unsigned r = (u + 0x7fffu + ((u >> 16) & 1u)) >> 16;
  return (unsigned short)r;
}
__device__ __forceinline__ float b2f_lo(unsigned u) { return __uint_as_float(u << 16); }
__device__ __forceinline__ float b2f_hi(unsigned u) { return __uint_as_float(u & 0xffff0000u); }
__device__ __forceinline__ float lrelu(float a) { return fmaxf(a, 0.f) + NEG_SLOPE * fminf(a, 0.f); }

// ---------------- CSR build ----------------
__global__ void zero_deg(int* __restrict__ deg) {
  int i = blockIdx.x * 256 + threadIdx.x;
  if (i < NN) deg[i] = 0;
}
__global__ void deg_hist(const int* __restrict__ dst, int* __restrict__ deg) {
  int e = blockIdx.x * 256 + threadIdx.x;
  if (e < NE) atomicAdd(&deg[dst[e]], 1);
}
__global__ __launch_bounds__(64) void scan_rowptr(const int* __restrict__ deg,
                                                  int* __restrict__ rowptr) {
  int lane = threadIdx.x;
  int carry = 0;
  for (int base = 0; base < NN; base += 64) {
    int i = base + lane;
    int v = (i < NN) ? deg[i] : 0;
    int s = v;
#pragma unroll
    for (int off = 1; off < 64; off <<= 1) {
      int t = __shfl_up(s, off);
      if (lane >= off) s += t;
    }
    if (i < NN) rowptr[i] = carry + s - v;
    carry += __shfl(s, 63);
  }
  if (lane == 0) rowptr[NN] = carry;
}
__global__ void copy_cursor(const int* __restrict__ rowptr, int* __restrict__ cursor) {
  int i = blockIdx.x * 256 + threadIdx.x;
  if (i < NN) cursor[i] = rowptr[i];
}
__global__ void csr_fill(const int* __restrict__ dst, int* __restrict__ cursor,
                         int* __restrict__ csr_e) {
  int e = blockIdx.x * 256 + threadIdx.x;
  if (e >= NE) return;
  int pos = atomicAdd(&cursor[dst[e]], 1);
  csr_e[pos] = e;
}

// ---------------- conversions ----------------
// x [NN][256] fp32 -> Xb [MPAD][256] bf16 (pad rows zero)
__global__ void cvt_x(const float* __restrict__ x, short* __restrict__ Xb) {
  int i = blockIdx.x * 256 + threadIdx.x;
  int base = i * 4;
  if (base >= MPAD * INC) return;
  ushort4 o;
  if (base < NN * INC) {
    float4 v = *(const float4*)(x + base);
    o.x = f2b(v.x); o.y = f2b(v.y); o.z = f2b(v.z); o.w = f2b(v.w);
  } else {
    o.x = o.y = o.z = o.w = 0;
  }
  *(ushort4*)(Xb + base) = o;
}

// src [K][Nsrc] fp32 -> dst [Nsrc][K] bf16 (transpose + convert); grid (Nsrc/32, K/32)
__global__ __launch_bounds__(256) void transpose_cvt(const float* __restrict__ src,
                                                     short* __restrict__ dst,
                                                     int K, int Nsrc) {
  __shared__ float tile[32][33];
  int tx = threadIdx.x & 31, ty = threadIdx.x >> 5;
  int nb = blockIdx.x * 32, kb = blockIdx.y * 32;
#pragma unroll
  for (int i = 0; i < 4; i++)
    tile[ty + i * 8][tx] = src[(size_t)(kb + ty + i * 8) * Nsrc + nb + tx];
  __syncthreads();
#pragma unroll
  for (int i = 0; i < 4; i++)
    dst[(size_t)(nb + ty + i * 8) * K + kb + tx] = (short)f2b(tile[tx][ty + i * 8]);
}

__global__ void zero_s(short* __restrict__ p, int n) {
  int i = blockIdx.x * 256 + threadIdx.x;
  if (i < n) p[i] = 0;
}

// ---------------- bf16 MFMA GEMM ----------------
// C[M][ldc] = Xb[Mpad][K] (bf16 rows) x Wt[N][K] (bf16 rows = B^T)
// tile 128x128, 4 waves (2x2), BK=32, mfma_f32_16x16x32_bf16.
// BF16OUT: write bf16, else fp32. Stores guarded by gr<M, gc<nvalid.
template<int BF16OUT>
__global__ __launch_bounds__(256) void gemm_bf16(const short* __restrict__ Xb,
                                                 const short* __restrict__ Wt,
                                                 void* __restrict__ Cout,
                                                 int M, int K, int ldc, int nvalid) {
  __shared__ short As[4096];  // [kc 0..3][row 0..127][8]
  __shared__ short Bs[4096];
  const int t = threadIdx.x;
  const int lane = t & 63;
  const int w = t >> 6;
  const int wr = w >> 1, wc = w & 1;
  const int row0 = blockIdx.y * 128;
  const int col0 = blockIdx.x * 128;
  const int r_st = t & 127;
  const int kc_st = t >> 7;   // 0 or 1
  f32x4 acc[4][4] = {};
  for (int k0 = 0; k0 < K; k0 += 32) {
    bf16x8 va0 = *(const bf16x8*)(Xb + (size_t)(row0 + r_st) * K + k0 + kc_st * 8);
    bf16x8 va1 = *(const bf16x8*)(Xb + (size_t)(row0 + r_st) * K + k0 + (kc_st + 2) * 8);
    bf16x8 vb0 = *(const bf16x8*)(Wt + (size_t)(col0 + r_st) * K + k0 + kc_st * 8);
    bf16x8 vb1 = *(const bf16x8*)(Wt + (size_t)(col0 + r_st) * K + k0 + (kc_st + 2) * 8);
    __syncthreads();  // previous iteration's ds_reads complete
    *(bf16x8*)&As[(kc_st)     * 1024 + r_st * 8] = va0;
    *(bf16x8*)&As[(kc_st + 2) * 1024 + r_st * 8] = va1;
    *(bf16x8*)&Bs[(kc_st)     * 1024 + r_st * 8] = vb0;
    *(bf16x8*)&Bs[(kc_st + 2) * 1024 + r_st * 8] = vb1;
    __syncthreads();
    bf16x8 af[4], bfr[4];
#pragma unroll
    for (int i = 0; i < 4; i++)
      af[i] = *(const bf16x8*)&As[(lane >> 4) * 1024 + (wr * 64 + i * 16 + (lane & 15)) * 8];
#pragma unroll
    for (int j = 0; j < 4; j++)
      bfr[j] = *(const bf16x8*)&Bs[(lane >> 4) * 1024 + (wc * 64 + j * 16 + (lane & 15)) * 8];
#pragma unroll
    for (int i = 0; i < 4; i++)
#pragma unroll
      for (int j = 0; j < 4; j++)
        acc[i][j] = __builtin_amdgcn_mfma_f32_16x16x32_bf16(af[i], bfr[j], acc[i][j], 0, 0, 0);
  }
  // C/D layout (m89-verified): col = lane&15, row = (lane>>4)*4 + reg
#pragma unroll
  for (int i = 0; i < 4; i++) {
    int rb = row0 + wr * 64 + i * 16 + (lane >> 4) * 4;
#pragma unroll
    for (int reg = 0; reg < 4; reg++) {
      int gr = rb + reg;
      if (gr < M) {
#pragma unroll
        for (int j = 0; j < 4; j++) {
          int gc = col0 + wc * 64 + j * 16 + (lane & 15);
          if (gc < nvalid) {
            if (BF16OUT) ((short*)Cout)[(size_t)gr * ldc + gc] = (short)f2b(acc[i][j][reg]);
            else         ((float*)Cout)[(size_t)gr * ldc + gc] = acc[i][j][reg];
          }
        }
      }
    }
  }
}

// ---------------- layer-1 edge scores (wave per edge, bf16 features) ----------------
__global__ __launch_bounds__(256) void edge1_e(const int* __restrict__ src, const int* __restrict__ dst,
                                               const short* __restrict__ xlr,
                                               const float* __restrict__ att, float* __restrict__ e1) {
  const int lane = threadIdx.x & 63;
  const int e = blockIdx.x * 4 + (threadIdx.x >> 6);
  if (e >= NE) return;
  int s = src[e], d = dst[e];
  const uint4* xls = (const uint4*)(xlr + (size_t)s * 2048);         // xl row (cols 0..1023)
  const uint4* xrd = (const uint4*)(xlr + (size_t)d * 2048 + 1024);  // xr row (cols 1024..2047)
  uint4 la = xls[lane], lb = xls[64 + lane];
  uint4 ra = xrd[lane], rb = xrd[64 + lane];
  const float4* a4 = (const float4*)att;
  float4 t00 = a4[lane * 2], t01 = a4[lane * 2 + 1];
  float4 t10 = a4[128 + lane * 2], t11 = a4[128 + lane * 2 + 1];
  float p0, p1;
  {
    float c0 = lrelu(b2f_lo(la.x) + b2f_lo(ra.x)) * t00.x;
    c0 += lrelu(b2f_hi(la.x) + b2f_hi(ra.x)) * t00.y;
    c0 += lrelu(b2f_lo(la.y) + b2f_lo(ra.y)) * t00.z;
    c0 += lrelu(b2f_hi(la.y) + b2f_hi(ra.y)) * t00.w;
    c0 += lrelu(b2f_lo(la.z) + b2f_lo(ra.z)) * t01.x;
    c0 += lrelu(b2f_hi(la.z) + b2f_hi(ra.z)) * t01.y;
    c0 += lrelu(b2f_lo(la.w) + b2f_lo(ra.w)) * t01.z;
    c0 += lrelu(b2f_hi(la.w) + b2f_hi(ra.w)) * t01.w;
    p0 = c0;
  }
  {
    float c1 = lrelu(b2f_lo(lb.x) + b2f_lo(rb.x)) * t10.x;
    c1 += lrelu(b2f_hi(lb.x) + b2f_hi(rb.x)) * t10.y;
    c1 += lrelu(b2f_lo(lb.y) + b2f_lo(rb.y)) * t10.z;
    c1 += lrelu(b2f_hi(lb.y) + b2f_hi(rb.y)) * t10.w;
    c1 += lrelu(b2f_lo(lb.z) + b2f_lo(rb.z)) * t11.x;
    c1 += lrelu(b2f_hi(lb.z) + b2f_hi(rb.z)) * t11.y;
    c1 += lrelu(b2f_lo(lb.w) + b2f_lo(rb.w)) * t11.z;
    c1 += lrelu(b2f_hi(lb.w) + b2f_hi(rb.w)) * t11.w;
    p1 = c1;
  }
#pragma unroll
  for (int off = 8; off > 0; off >>= 1) {
    p0 += __shfl_xor(p0, off);
    p1 += __shfl_xor(p1, off);
  }
  if ((lane & 15) == 0) {
    e1[e * 8 + (lane >> 4)] = p0;       // heads 0..3
    e1[e * 8 + 4 + (lane >> 4)] = p1;   // heads 4..7
  }
}

// ---------------- layer-1 segment softmax (thread per (dst,head)) ----------------
__global__ void node1_softmax(const int* __restrict__ rowptr, const int* __restrict__ csr_e,
                              float* __restrict__ e1) {
  int i = blockIdx.x * 256 + threadIdx.x;
  if (i >= NN * H) return;
  int d = i >> 3, h = i & 7;
  int jb = rowptr[d], je = rowptr[d + 1];
  if (jb == je) return;
  float m = -3.4e38f;
  for (int j = jb; j < je; j++) m = fmaxf(m, e1[csr_e[j] * 8 + h]);
  float s = 0.f;
  for (int j = jb; j < je; j++) s += expf(e1[csr_e[j] * 8 + h] - m);
  float inv = 1.f / (s + 1e-16f);
  for (int j = jb; j < je; j++) {
    int e = csr_e[j];
    e1[e * 8 + h] = expf(e1[e * 8 + h] - m) * inv;
  }
}

// ---------------- layer-1 aggregation + bias + ELU -> bf16 h1 (block per dst) ----------------
__global__ __launch_bounds__(256) void agg1(const int* __restrict__ rowptr, const int* __restrict__ csr_e,
                                            const int* __restrict__ src, const short* __restrict__ xlr,
                                            const float* __restrict__ e1, const float* __restrict__ b1,
                                            short* __restrict__ h1b) {
  int d = blockIdx.x;
  int t = threadIdx.x;
  int head = t >> 5;  // (t*4)>>7
  float4 acc = make_float4(0.f, 0.f, 0.f, 0.f);
  int jb = rowptr[d], je = rowptr[d + 1];
  for (int j = jb; j < je; j++) {
    int e = csr_e[j];
    int s = src[e];
    float alpha = e1[e * 8 + head];
    uint2 v = *(const uint2*)(xlr + (size_t)s * 2048 + t * 4);
    acc.x += alpha * b2f_lo(v.x); acc.y += alpha * b2f_hi(v.x);
    acc.z += alpha * b2f_lo(v.y); acc.w += alpha * b2f_hi(v.y);
  }
  float4 b = *(const float4*)(b1 + t * 4);
  acc.x += b.x; acc.y += b.y; acc.z += b.z; acc.w += b.w;
  acc.x = acc.x > 0.f ? acc.x : expm1f(acc.x);
  acc.y = acc.y > 0.f ? acc.y : expm1f(acc.y);
  acc.z = acc.z > 0.f ? acc.z : expm1f(acc.z);
  acc.w = acc.w > 0.f ? acc.w : expm1f(acc.w);
  ushort4 o;
  o.x = f2b(acc.x); o.y = f2b(acc.y); o.z = f2b(acc.z); o.w = f2b(acc.w);
  *(ushort4*)(h1b + (size_t)d * 1024 + t * 4) = o;
}

// ---------------- layer-2 edge scores (32 lanes per edge) ----------------
__global__ __launch_bounds__(256) void edge2_e(const int* __restrict__ src, const int* __restrict__ dst,
                                               const float* __restrict__ xlr2,
                                               const float* __restrict__ att2, float* __restrict__ e2) {
  int t = threadIdx.x;
  int e = blockIdx.x * 8 + (t >> 5);
  int c = t & 31;
  if (e >= NE) return;
  int s = src[e], d = dst[e];
  float a = xlr2[s * 64 + c] + xlr2[d * 64 + 32 + c];
  a = lrelu(a);
  float v = a * att2[c];
#pragma unroll
  for (int off = 16; off > 0; off >>= 1) v += __shfl_xor(v, off);
  if (c == 0) e2[e] = v;
}

__global__ void node2_softmax(const int* __restrict__ rowptr, const int* __restrict__ csr_e,
                              float* __restrict__ e2) {
  int d = blockIdx.x * 256 + threadIdx.x;
  if (d >= NN) return;
  int jb = rowptr[d], je = rowptr[d + 1];
  if (jb == je) return;
  float m = -3.4e38f;
  for (int j = jb; j < je; j++) m = fmaxf(m, e2[csr_e[j]]);
  float s = 0.f;
  for (int j = jb; j < je; j++) s += expf(e2[csr_e[j]] - m);
  float inv = 1.f / (s + 1e-16f);
  for (int j = jb; j < je; j++) {
    int e = csr_e[j];
    e2[e] = expf(e2[e] - m) * inv;
  }
}

// ---------------- layer-2 agg + bias + log_softmax (32 lanes per dst) ----------------
__global__ __launch_bounds__(256) void agg2(const int* __restrict__ rowptr, const int* __restrict__ csr_e,
                                            const int* __restrict__ src, const float* __restrict__ xlr2,
                                            const float* __restrict__ e2, const float* __restrict__ b2,
                                            float* __restrict__ out) {
  int t = threadIdx.x;
  int d = blockIdx.x * 8 + (t >> 5);
  int c = t & 31;
  if (d >= NN) return;
  float acc = 0.f;
  int jb = rowptr[d], je = rowptr[d + 1];
  for (int j = jb; j < je; j++) {
    int e = csr_e[j];
    int s = src[e];
    acc += e2[e] * xlr2[s * 64 + c];
  }
  float v = acc + b2[c];
  float m = v;
#pragma unroll
  for (int off = 16; off > 0; off >>= 1) m = fmaxf(m, __shfl_xor(m, off));
  float ex = expf(v - m);
  float sum = ex;
#pragma unroll
  for (int off = 16; off > 0; off >>= 1) sum += __shfl_xor(sum, off);
  out[d * 32 + c] = v - m - logf(sum);
}

extern "C" void kernel_launch(void* const* d_in, const int* in_sizes, int n_in,
                              void* d_out, int out_size, void* d_ws, size_t ws_size,
                              hipStream_t stream) {
  const float* x    = (const float*)d_in[0];
  const int*   ei   = (const int*)d_in[1];
  const float* W1l  = (const float*)d_in[2];
  const float* W1r  = (const float*)d_in[3];
  const float* att1 = (const float*)d_in[4];
  const float* b1   = (const float*)d_in[5];
  const float* W2l  = (const float*)d_in[6];
  const float* W2r  = (const float*)d_in[7];
  const float* att2 = (const float*)d_in[8];
  const float* b2   = (const float*)d_in[9];
  float* out = (float*)d_out;

  // workspace layout
  short* Xb   = (short*)d_ws;                     // MPAD*256
  short* Wt1  = Xb + (size_t)MPAD * 256;          // 2048*256 (rows 0..1023 = W1l^T, 1024..2047 = W1r^T)
  short* Wt2  = Wt1 + (size_t)2048 * 256;         // 128*1024 (rows 0..31 W2l^T, 32..63 W2r^T, 64..127 zero)
  short* xlr  = Wt2 + (size_t)128 * 1024;         // NN*2048 bf16 (xl | xr)
  short* h1b  = xlr + (size_t)NN * 2048;          // MPAD*1024 bf16 (pad rows garbage, discarded)
  float* e1   = (float*)(h1b + (size_t)MPAD * 1024); // NE*8
  float* e2   = e1 + (size_t)NE * 8;              // NE
  float* xlr2 = e2 + NE;                          // NN*64
  int* deg    = (int*)(xlr2 + (size_t)NN * 64);   // NN
  int* rowptr = deg + NN;                         // NN+1
  int* cursor = rowptr + NN + 1;                  // NN
  int* csr_e  = cursor + NN;                      // NE

  const int* src = ei;
  const int* dst = ei + NE;

  // CSR build
  zero_deg<<<(NN + 255) / 256, 256, 0, stream>>>(deg);
  deg_hist<<<(NE + 255) / 256, 256, 0, stream>>>(dst, deg);
  scan_rowptr<<<1, 64, 0, stream>>>(deg, rowptr);
  copy_cursor<<<(NN + 255) / 256, 256, 0, stream>>>(rowptr, cursor);
  csr_fill<<<(NE + 255) / 256, 256, 0, stream>>>(dst, cursor, csr_e);

  // conversions
  cvt_x<<<(MPAD * 256 / 4 + 255) / 256, 256, 0, stream>>>(x, Xb);
  {
    dim3 g(1024 / 32, 256 / 32);
    transpose_cvt<<<g, 256, 0, stream>>>(W1l, Wt1, 256, 1024);
    transpose_cvt<<<g, 256, 0, stream>>>(W1r, Wt1 + (size_t)1024 * 256, 256, 1024);
  }
  {
    dim3 g(32 / 32, 1024 / 32);
    transpose_cvt<<<g, 256, 0, stream>>>(W2l, Wt2, 1024, 32);
    transpose_cvt<<<g, 256, 0, stream>>>(W2r, Wt2 + (size_t)32 * 1024, 1024, 32);
    zero_s<<<(64 * 1024 + 255) / 256, 256, 0, stream>>>(Wt2 + (size_t)64 * 1024, 64 * 1024);
  }

  // layer-1 GEMM: [MPAD x 256] x [2048 x 256]^T -> xlr bf16 [NN][2048]
  {
    dim3 g(2048 / 128, MPAD / 128);
    gemm_bf16<1><<<g, 256, 0, stream>>>(Xb, Wt1, xlr, NN, 256, 2048, 2048);
  }

  // layer-1 attention
  edge1_e<<<NE / 4, 256, 0, stream>>>(src, dst, xlr, att1, e1);
  node1_softmax<<<(NN * H + 255) / 256, 256, 0, stream>>>(rowptr, csr_e, e1);
  agg1<<<NN, 256, 0, stream>>>(rowptr, csr_e, src, xlr, e1, b1, h1b);

  // layer-2 GEMM: [MPAD x 1024] x [128 x 1024]^T -> xlr2 fp32 [NN][64]
  {
    dim3 g(1, MPAD / 128);
    gemm_bf16<0><<<g, 256, 0, stream>>>(h1b, Wt2, xlr2, NN, 1024, 64, 64);
  }

  // layer-2 attention
  edge2_e<<<NE / 8, 256, 0, stream>>>(src, dst, xlr2, att2, e2);
  node2_softmax<<<(NN + 255) / 256, 256, 0, stream>>>(rowptr, csr_e, e2);
  agg2<<<(NN + 7) / 8, 256, 0, stream>>>(rowptr, csr_e, src, xlr2, e2, b2, out);
}

// Round 4
// 403.636 us; speedup vs baseline: 2.7683x; 1.2639x over previous
//
#include <hip/hip_runtime.h>
#include <hip/hip_bf16.h>

constexpr int NN   = 10000;
constexpr int NE   = 160000;
constexpr int INC  = 256;
constexpr int H    = 8;
constexpr int D1   = 1024;     // 8 heads x 128
constexpr int OUTC = 32;
constexpr int MPAD = 10112;    // 79 * 128
constexpr float NEG_SLOPE = 0.2f;

typedef __attribute__((ext_vector_type(8))) short bf16x8;
typedef __attribute__((ext_vector_type(4))) float f32x4;

__device__ __forceinline__ unsigned short f2b(float f) {
  unsigned u = __float_as_uint(f);
  unsigned r = (u + 0x7fffu + ((u >> 16) & 1u)) >> 16;
  return (unsigned short)r;
}
__device__ __forceinline__ float b2f_lo(unsigned u) { return __uint_as_float(u << 16); }
__device__ __forceinline__ float b2f_hi(unsigned u) { return __uint_as_float(u & 0xffff0000u); }
__device__ __forceinline__ float lrelu(float a) { return fmaxf(a, 0.f) + NEG_SLOPE * fminf(a, 0.f); }

// ---------------- CSR build ----------------
__global__ void zero_deg(int* __restrict__ deg) {
  int i = blockIdx.x * 256 + threadIdx.x;
  if (i < NN) deg[i] = 0;
}
__global__ void deg_hist(const int* __restrict__ dst, int* __restrict__ deg) {
  int e = blockIdx.x * 256 + threadIdx.x;
  if (e < NE) atomicAdd(&deg[dst[e]], 1);
}
// exclusive scan -> rowptr[NN+1], also seeds cursor
__global__ __launch_bounds__(64) void scan_rowptr(const int* __restrict__ deg,
                                                  int* __restrict__ rowptr,
                                                  int* __restrict__ cursor) {
  int lane = threadIdx.x;
  int carry = 0;
  for (int base = 0; base < NN; base += 64) {
    int i = base + lane;
    int v = (i < NN) ? deg[i] : 0;
    int s = v;
#pragma unroll
    for (int off = 1; off < 64; off <<= 1) {
      int t = __shfl_up(s, off);
      if (lane >= off) s += t;
    }
    if (i < NN) { rowptr[i] = carry + s - v; cursor[i] = carry + s - v; }
    carry += __shfl(s, 63);
  }
  if (lane == 0) rowptr[NN] = carry;
}
__global__ void csr_fill(const int* __restrict__ dst, int* __restrict__ cursor,
                         int* __restrict__ csr_e) {
  int e = blockIdx.x * 256 + threadIdx.x;
  if (e >= NE) return;
  int pos = atomicAdd(&cursor[dst[e]], 1);
  csr_e[pos] = e;
}

// ---------------- conversions ----------------
__global__ void cvt_x(const float* __restrict__ x, short* __restrict__ Xb) {
  int i = blockIdx.x * 256 + threadIdx.x;
  int base = i * 4;
  if (base >= MPAD * INC) return;
  ushort4 o;
  if (base < NN * INC) {
    float4 v = *(const float4*)(x + base);
    o.x = f2b(v.x); o.y = f2b(v.y); o.z = f2b(v.z); o.w = f2b(v.w);
  } else {
    o.x = o.y = o.z = o.w = 0;
  }
  *(ushort4*)(Xb + base) = o;
}

// src [K][Nsrc] fp32 -> dst [Nsrc][K] bf16 (transpose + convert); grid (Nsrc/32, K/32)
__global__ __launch_bounds__(256) void transpose_cvt(const float* __restrict__ src,
                                                     short* __restrict__ dst,
                                                     int K, int Nsrc) {
  __shared__ float tile[32][33];
  int tx = threadIdx.x & 31, ty = threadIdx.x >> 5;
  int nb = blockIdx.x * 32, kb = blockIdx.y * 32;
#pragma unroll
  for (int i = 0; i < 4; i++)
    tile[ty + i * 8][tx] = src[(size_t)(kb + ty + i * 8) * Nsrc + nb + tx];
  __syncthreads();
#pragma unroll
  for (int i = 0; i < 4; i++)
    dst[(size_t)(nb + ty + i * 8) * K + kb + tx] = (short)f2b(tile[tx][ty + i * 8]);
}

__global__ void zero_s(short* __restrict__ p, int n) {
  int i = blockIdx.x * 256 + threadIdx.x;
  if (i < n) p[i] = 0;
}

// ---------------- bf16 MFMA GEMM ----------------
// C[M][ldc] = Xb[Mpad][K] x Wt[N][K]^T, tile 128x128, mfma_f32_16x16x32_bf16.
template<int BF16OUT>
__global__ __launch_bounds__(256) void gemm_bf16(const short* __restrict__ Xb,
                                                 const short* __restrict__ Wt,
                                                 void* __restrict__ Cout,
                                                 int M, int K, int ldc, int nvalid) {
  __shared__ short As[4096];
  __shared__ short Bs[4096];
  const int t = threadIdx.x;
  const int lane = t & 63;
  const int w = t >> 6;
  const int wr = w >> 1, wc = w & 1;
  const int row0 = blockIdx.y * 128;
  const int col0 = blockIdx.x * 128;
  const int r_st = t & 127;
  const int kc_st = t >> 7;
  f32x4 acc[4][4] = {};
  for (int k0 = 0; k0 < K; k0 += 32) {
    bf16x8 va0 = *(const bf16x8*)(Xb + (size_t)(row0 + r_st) * K + k0 + kc_st * 8);
    bf16x8 va1 = *(const bf16x8*)(Xb + (size_t)(row0 + r_st) * K + k0 + (kc_st + 2) * 8);
    bf16x8 vb0 = *(const bf16x8*)(Wt + (size_t)(col0 + r_st) * K + k0 + kc_st * 8);
    bf16x8 vb1 = *(const bf16x8*)(Wt + (size_t)(col0 + r_st) * K + k0 + (kc_st + 2) * 8);
    __syncthreads();
    *(bf16x8*)&As[(kc_st)     * 1024 + r_st * 8] = va0;
    *(bf16x8*)&As[(kc_st + 2) * 1024 + r_st * 8] = va1;
    *(bf16x8*)&Bs[(kc_st)     * 1024 + r_st * 8] = vb0;
    *(bf16x8*)&Bs[(kc_st + 2) * 1024 + r_st * 8] = vb1;
    __syncthreads();
    bf16x8 af[4], bfr[4];
#pragma unroll
    for (int i = 0; i < 4; i++)
      af[i] = *(const bf16x8*)&As[(lane >> 4) * 1024 + (wr * 64 + i * 16 + (lane & 15)) * 8];
#pragma unroll
    for (int j = 0; j < 4; j++)
      bfr[j] = *(const bf16x8*)&Bs[(lane >> 4) * 1024 + (wc * 64 + j * 16 + (lane & 15)) * 8];
#pragma unroll
    for (int i = 0; i < 4; i++)
#pragma unroll
      for (int j = 0; j < 4; j++)
        acc[i][j] = __builtin_amdgcn_mfma_f32_16x16x32_bf16(af[i], bfr[j], acc[i][j], 0, 0, 0);
  }
#pragma unroll
  for (int i = 0; i < 4; i++) {
    int rb = row0 + wr * 64 + i * 16 + (lane >> 4) * 4;
#pragma unroll
    for (int reg = 0; reg < 4; reg++) {
      int gr = rb + reg;
      if (gr < M) {
#pragma unroll
        for (int j = 0; j < 4; j++) {
          int gc = col0 + wc * 64 + j * 16 + (lane & 15);
          if (gc < nvalid) {
            if (BF16OUT) ((short*)Cout)[(size_t)gr * ldc + gc] = (short)f2b(acc[i][j][reg]);
            else         ((float*)Cout)[(size_t)gr * ldc + gc] = acc[i][j][reg];
          }
        }
      }
    }
  }
}

// ---------------- fused layer-1 attention: scores + online softmax + agg + bias + ELU ----------------
// block per dst node, 256 threads; thread t owns channels 4t..4t+3 (head = t>>5).
// In-edges processed in chunks of CH; gathered xl rows staged in LDS once and
// used for BOTH the score and the weighted accumulation.
__global__ __launch_bounds__(256) void attn1(const int* __restrict__ rowptr, const int* __restrict__ csr_e,
                                             const int* __restrict__ src, const short* __restrict__ xlr,
                                             const float* __restrict__ att, const float* __restrict__ b1,
                                             short* __restrict__ h1b) {
  constexpr int CH = 16;
  __shared__ short xs[CH][1024];   // 32 KB: chunk of gathered xl rows (bf16)
  __shared__ float sc[CH][8];      // per-edge per-head scores
  __shared__ int   sarr[CH];       // src ids of chunk
  const int d = blockIdx.x;
  const int t = threadIdx.x;
  const int h = t >> 5;
  // xr[d] channels 4t..4t+3
  uint2 xru = *(const uint2*)(xlr + (size_t)d * 2048 + 1024 + 4 * t);
  float xr0 = b2f_lo(xru.x), xr1 = b2f_hi(xru.x), xr2v = b2f_lo(xru.y), xr3 = b2f_hi(xru.y);
  float4 at = *(const float4*)(att + 4 * t);
  float m = -3.4e38f, den = 0.f;
  float4 acc = make_float4(0.f, 0.f, 0.f, 0.f);
  const int jb = rowptr[d], je = rowptr[d + 1];
  for (int j0 = jb; j0 < je; j0 += CH) {
    const int n = min(CH, je - j0);
    __syncthreads();                       // protect xs/sc/sarr from prev chunk readers
    if (t < n) sarr[t] = src[csr_e[j0 + t]];
    __syncthreads();
    for (int k = 0; k < n; k++) {          // stage xl rows (1 x 8B load per thread per edge)
      *(uint2*)&xs[k][4 * t] = *(const uint2*)(xlr + (size_t)sarr[k] * 2048 + 4 * t);
    }
    __syncthreads();
    for (int k = 0; k < n; k++) {          // scores
      uint2 v = *(const uint2*)&xs[k][4 * t];
      float p = lrelu(b2f_lo(v.x) + xr0) * at.x;
      p += lrelu(b2f_hi(v.x) + xr1) * at.y;
      p += lrelu(b2f_lo(v.y) + xr2v) * at.z;
      p += lrelu(b2f_hi(v.y) + xr3) * at.w;
#pragma unroll
      for (int off = 16; off > 0; off >>= 1) p += __shfl_xor(p, off);
      if ((t & 31) == 0) sc[k][h] = p;
    }
    __syncthreads();
    // online softmax update + aggregation (den identical across the 32 lanes of a head)
    float cmax = -3.4e38f;
    for (int k = 0; k < n; k++) cmax = fmaxf(cmax, sc[k][h]);
    float newm = fmaxf(m, cmax);
    float r = __expf(m - newm);            // 0 on first chunk (m=-3.4e38)
    acc.x *= r; acc.y *= r; acc.z *= r; acc.w *= r; den *= r;
    m = newm;
    for (int k = 0; k < n; k++) {
      float w = __expf(sc[k][h] - m);
      den += w;
      uint2 v = *(const uint2*)&xs[k][4 * t];
      acc.x += w * b2f_lo(v.x); acc.y += w * b2f_hi(v.x);
      acc.z += w * b2f_lo(v.y); acc.w += w * b2f_hi(v.y);
    }
  }
  float inv = 1.f / (den + 1e-16f);
  float4 b = *(const float4*)(b1 + 4 * t);
  float o0 = acc.x * inv + b.x, o1 = acc.y * inv + b.y;
  float o2 = acc.z * inv + b.z, o3 = acc.w * inv + b.w;
  o0 = o0 > 0.f ? o0 : expm1f(o0);
  o1 = o1 > 0.f ? o1 : expm1f(o1);
  o2 = o2 > 0.f ? o2 : expm1f(o2);
  o3 = o3 > 0.f ? o3 : expm1f(o3);
  ushort4 o;
  o.x = f2b(o0); o.y = f2b(o1); o.z = f2b(o2); o.w = f2b(o3);
  *(ushort4*)(h1b + (size_t)d * 1024 + 4 * t) = o;
}

// ---------------- fused layer-2: scores + online softmax + agg + bias + log_softmax ----------------
// 32 lanes per dst node (8 nodes per block). Single gather per edge feeds both
// score and aggregation.
__global__ __launch_bounds__(256) void attn2(const int* __restrict__ rowptr, const int* __restrict__ csr_e,
                                             const int* __restrict__ src, const float* __restrict__ xlr2,
                                             const float* __restrict__ att2, const float* __restrict__ b2,
                                             float* __restrict__ out) {
  const int t = threadIdx.x;
  const int d = blockIdx.x * 8 + (t >> 5);
  const int c = t & 31;
  if (d >= NN) return;
  const float xr = xlr2[d * 64 + 32 + c];
  const float a2 = att2[c];
  float m = -3.4e38f, den = 0.f, acc = 0.f;
  const int jb = rowptr[d], je = rowptr[d + 1];
  for (int j = jb; j < je; j++) {
    int e = csr_e[j];
    int s = src[e];
    float xv = xlr2[s * 64 + c];
    float p = a2 * lrelu(xv + xr);
#pragma unroll
    for (int off = 16; off > 0; off >>= 1) p += __shfl_xor(p, off);
    if (p > m) {                           // uniform across the 32-lane group
      float r = __expf(m - p);
      acc *= r; den *= r; m = p;
    }
    float w = __expf(p - m);
    den += w;
    acc += w * xv;
  }
  float v = acc / (den + 1e-16f) + b2[c];
  float mx = v;
#pragma unroll
  for (int off = 16; off > 0; off >>= 1) mx = fmaxf(mx, __shfl_xor(mx, off));
  float ex = __expf(v - mx);
  float sum = ex;
#pragma unroll
  for (int off = 16; off > 0; off >>= 1) sum += __shfl_xor(sum, off);
  out[d * 32 + c] = v - mx - logf(sum);
}

extern "C" void kernel_launch(void* const* d_in, const int* in_sizes, int n_in,
                              void* d_out, int out_size, void* d_ws, size_t ws_size,
                              hipStream_t stream) {
  const float* x    = (const float*)d_in[0];
  const int*   ei   = (const int*)d_in[1];
  const float* W1l  = (const float*)d_in[2];
  const float* W1r  = (const float*)d_in[3];
  const float* att1 = (const float*)d_in[4];
  const float* b1   = (const float*)d_in[5];
  const float* W2l  = (const float*)d_in[6];
  const float* W2r  = (const float*)d_in[7];
  const float* att2 = (const float*)d_in[8];
  const float* b2   = (const float*)d_in[9];
  float* out = (float*)d_out;

  // workspace layout
  short* Xb   = (short*)d_ws;                     // MPAD*256
  short* Wt1  = Xb + (size_t)MPAD * 256;          // 2048*256
  short* Wt2  = Wt1 + (size_t)2048 * 256;         // 128*1024
  short* xlr  = Wt2 + (size_t)128 * 1024;         // NN*2048 bf16 (xl | xr)
  short* h1b  = xlr + (size_t)NN * 2048;          // MPAD*1024 bf16
  float* xlr2 = (float*)(h1b + (size_t)MPAD * 1024); // NN*64
  int* deg    = (int*)(xlr2 + (size_t)NN * 64);   // NN
  int* rowptr = deg + NN;                         // NN+1
  int* cursor = rowptr + NN + 1;                  // NN
  int* csr_e  = cursor + NN;                      // NE

  const int* src = ei;
  const int* dst = ei + NE;

  // CSR build
  zero_deg<<<(NN + 255) / 256, 256, 0, stream>>>(deg);
  deg_hist<<<(NE + 255) / 256, 256, 0, stream>>>(dst, deg);
  scan_rowptr<<<1, 64, 0, stream>>>(deg, rowptr, cursor);
  csr_fill<<<(NE + 255) / 256, 256, 0, stream>>>(dst, cursor, csr_e);

  // conversions
  cvt_x<<<(MPAD * 256 / 4 + 255) / 256, 256, 0, stream>>>(x, Xb);
  {
    dim3 g(1024 / 32, 256 / 32);
    transpose_cvt<<<g, 256, 0, stream>>>(W1l, Wt1, 256, 1024);
    transpose_cvt<<<g, 256, 0, stream>>>(W1r, Wt1 + (size_t)1024 * 256, 256, 1024);
  }
  {
    dim3 g(32 / 32, 1024 / 32);
    transpose_cvt<<<g, 256, 0, stream>>>(W2l, Wt2, 1024, 32);
    transpose_cvt<<<g, 256, 0, stream>>>(W2r, Wt2 + (size_t)32 * 1024, 1024, 32);
    zero_s<<<(64 * 1024 + 255) / 256, 256, 0, stream>>>(Wt2 + (size_t)64 * 1024, 64 * 1024);
  }

  // layer-1 GEMM -> xlr bf16 [NN][2048]
  {
    dim3 g(2048 / 128, MPAD / 128);
    gemm_bf16<1><<<g, 256, 0, stream>>>(Xb, Wt1, xlr, NN, 256, 2048, 2048);
  }

  // fused layer-1 attention
  attn1<<<NN, 256, 0, stream>>>(rowptr, csr_e, src, xlr, att1, b1, h1b);

  // layer-2 GEMM -> xlr2 fp32 [NN][64]
  {
    dim3 g(1, MPAD / 128);
    gemm_bf16<0><<<g, 256, 0, stream>>>(h1b, Wt2, xlr2, NN, 1024, 64, 64);
  }

  // fused layer-2 attention + log_softmax
  attn2<<<(NN + 7) / 8, 256, 0, stream>>>(rowptr, csr_e, src, xlr2, att2, b2, out);
}